// Round 3
// baseline (1240.378 us; speedup 1.0000x reference)
//
#include <hip/hip_runtime.h>
#include <hip/hip_bf16.h>
#include <math.h>

// SeaLiceGLKAN — fp32 inputs, fp32 output, fp32 internal compute.
// CSR by dst built per-launch; one wave (64 lanes) per node, lane = H dim.

constexpr int cB = 2, cT = 4, cN = 10000, cF = 16, cH = 64, cE = 160000, cNB = 8, cK = 3;
constexpr int cBN = cB * cN;      // 20000
constexpr int cBNH = cBN * cH;    // 1,280,000

typedef const float* fp;

__device__ __forceinline__ float wsum(float v) {
#pragma unroll
  for (int o = 1; o < 64; o <<= 1) v += __shfl_xor(v, o, 64);
  return v;
}
__device__ __forceinline__ float wmax(float v) {
#pragma unroll
  for (int o = 1; o < 64; o <<= 1) v = fmaxf(v, __shfl_xor(v, o, 64));
  return v;
}

// ---------------- CSR build ----------------
__global__ void k_zero_i32(int* p, int n) {
  int i = blockIdx.x * 256 + threadIdx.x;
  if (i < n) p[i] = 0;
}

__global__ void k_count(const int* dst, int* counts) {
  int e = blockIdx.x * 256 + threadIdx.x;
  if (e < cE) atomicAdd(&counts[dst[e]], 1);
}

__global__ void k_scan(const int* counts, int* row_ptr, int* cursor) {
  __shared__ int part[1024];
  int t = threadIdx.x;
  const int CH = (cN + 1023) / 1024;  // 10
  int s = 0;
  for (int i = 0; i < CH; i++) {
    int idx = t * CH + i;
    if (idx < cN) s += counts[idx];
  }
  part[t] = s;
  __syncthreads();
  for (int off = 1; off < 1024; off <<= 1) {
    int v = (t >= off) ? part[t - off] : 0;
    __syncthreads();
    part[t] += v;
    __syncthreads();
  }
  int excl = (t == 0) ? 0 : part[t - 1];
  for (int i = 0; i < CH; i++) {
    int idx = t * CH + i;
    if (idx < cN) {
      row_ptr[idx] = excl;
      cursor[idx] = excl;
      excl += counts[idx];
    }
  }
  if (t == 1023) row_ptr[cN] = part[1023];
}

// scatter edges into CSR order; fuse the larval-transport gate MLP (per-edge, t-invariant)
__global__ void k_scatter(const int* src, const int* dst, fp ea, fp w1, fp b1, fp w2, fp b2,
                          int* cursor, int* esrc, float* gcsr) {
  int e = blockIdx.x * 256 + threadIdx.x;
  if (e >= cE) return;
  float a0 = ea[e * 4 + 0], a1 = ea[e * 4 + 1], a2 = ea[e * 4 + 2], a3 = ea[e * 4 + 3];
  float acc = b2[0];
#pragma unroll
  for (int j = 0; j < 16; j++) {
    float tv = b1[j] + a0 * w1[j] + a1 * w1[16 + j] + a2 * w1[32 + j] + a3 * w1[48 + j];
    acc += tanhf(tv) * w2[j];
  }
  float g = 1.f / (1.f + expf(-acc));
  int p = atomicAdd(&cursor[dst[e]], 1);
  esrc[p] = src[e];
  gcsr[p] = g;
}

__global__ void k_init_h(float* h, fp h0) {
  int i = blockIdx.x * 256 + threadIdx.x;
  if (i < cBNH) h[i] = h0[i & 63];
}

// ---------------- per-step kernels (wave per node) ----------------
__global__ __launch_bounds__(256) void k_hop_mat(const float* vin, fp Wh, fp asrc, fp adst,
                                                 float* hw, float* ssrc, float* sdst) {
  __shared__ float s_v[4][cH];
  int w = threadIdx.x >> 6, lane = threadIdx.x & 63;
  int node = blockIdx.x * 4 + w;
  s_v[w][lane] = vin[(size_t)node * cH + lane];
  __syncthreads();
  float acc = 0.f;
#pragma unroll 8
  for (int i = 0; i < cH; i++) acc += s_v[w][i] * Wh[i * cH + lane];
  hw[(size_t)node * cH + lane] = acc;
  float r1 = wsum(acc * asrc[lane]);
  float r2 = wsum(acc * adst[lane]);
  if (lane == 0) {
    ssrc[node] = r1;
    sdst[node] = r2;
  }
}

__global__ __launch_bounds__(256) void k_hop_agg(const float* hw, const float* ssrc,
                                                 const float* sdst, const int* row_ptr,
                                                 const int* esrc, float* cur, float* khout,
                                                 int hop) {
  int w = threadIdx.x >> 6, lane = threadIdx.x & 63;
  int node = blockIdx.x * 4 + w;
  int b = node / cN, n = node % cN;
  int r0 = row_ptr[n], r1 = row_ptr[n + 1];
  const float* sb = ssrc + (size_t)b * cN;
  float sd = sdst[node];
  float m = -INFINITY;
  for (int e = r0 + lane; e < r1; e += 64) {
    float ev = sb[esrc[e]] + sd;
    ev = ev > 0.f ? ev : 0.2f * ev;
    m = fmaxf(m, ev);
  }
  m = wmax(m);
  float den = 0.f, num = 0.f;
  const float* hwb = hw + (size_t)b * cN * cH;
  for (int e = r0; e < r1; e++) {
    int s = esrc[e];
    float ev = sb[s] + sd;
    ev = ev > 0.f ? ev : 0.2f * ev;
    float wgt = expf(ev - m);
    den += wgt;
    num += wgt * hwb[(size_t)s * cH + lane];
  }
  float cv = num / (den + 1e-16f);
  size_t gi = (size_t)node * cH + lane;
  cur[gi] = cv;
  khout[gi] = (hop == 0) ? cv : khout[gi] + cv;
}

__global__ __launch_bounds__(256) void k_larval(const float* h, const int* row_ptr,
                                                const int* esrc, const float* gcsr, float* agg) {
  int w = threadIdx.x >> 6, lane = threadIdx.x & 63;
  int node = blockIdx.x * 4 + w;
  int b = node / cN, n = node % cN;
  int r0 = row_ptr[n], r1 = row_ptr[n + 1];
  const float* hb = h + (size_t)b * cN * cH;
  float acc = 0.f;
  for (int e = r0; e < r1; e++) acc += gcsr[e] * hb[(size_t)esrc[e] * cH + lane];
  agg[(size_t)node * cH + lane] = acc;
}

// fused: encoder (fastkan) + larval matvec + liquid cell + LayerNorm + decoder
__global__ __launch_bounds__(256) void k_cell(fp x, int t, float* h, const float* khout,
                                              const float* agg, const int* row_ptr, fp W_lt,
                                              fp W_tau, fp b_tau, fp W_g, fp b_g, fp gamma,
                                              fp beta, fp c_enc, fp W_enc, fp b_enc, fp cdec,
                                              fp W_dec, fp b_dec, float* out) {
  __shared__ float s_z[4][133];
  __shared__ float s_a[4][cH];
  __shared__ float s_phi[4][cF * cNB];
  int w = threadIdx.x >> 6, lane = threadIdx.x & 63;
  int node = blockIdx.x * 4 + w;
  int b = node / cN, n = node % cN;
  size_t gi = (size_t)node * cH + lane;
  float hcur = h[gi];
  s_z[w][lane] = hcur;
  const float* xp = x + (((size_t)b * cT + t) * cN + n) * cF;
  if (lane < 5) s_z[w][64 + lane] = xp[8 + lane];
  s_a[w][lane] = agg[gi];
  // encoder RBF basis
  float ec0 = c_enc[0], ec7 = c_enc[cNB - 1];
  float inv_e = (float)(cNB - 1) / (ec7 - ec0);
#pragma unroll
  for (int j = 0; j < 2; j++) {
    int idx = lane * 2 + j;
    int f = idx >> 3, cb = idx & 7;
    float d = (xp[f] - c_enc[cb]) * inv_e;
    s_phi[w][idx] = expf(-d * d);
  }
  __syncthreads();
  // larval: (agg/(deg+1)) @ W_lt
  float deg = (float)(row_ptr[n + 1] - row_ptr[n]);
  float acc = 0.f;
#pragma unroll 8
  for (int i = 0; i < cH; i++) acc += s_a[w][i] * W_lt[i * cH + lane];
  float p = khout[gi] * (1.f / 3.f) + acc / (deg + 1.f);
  s_z[w][69 + lane] = p;
  // encoder matvec
  float u = b_enc[lane];
#pragma unroll 4
  for (int i = 0; i < cF * cNB; i++) u += s_phi[w][i] * W_enc[i * cH + lane];
  __syncthreads();
  float at = b_tau[lane], ag = b_g[lane];
  for (int r = 0; r < 133; r++) {
    float zv = s_z[w][r];
    at += zv * W_tau[r * cH + lane];
    ag += zv * W_g[r * cH + lane];
  }
  float tau = 1.f + 9.f / (1.f + expf(-at));
  float g = tanhf(ag);
  float hn = hcur + 0.25f * (g - hcur) / tau;
  float mu = wsum(hn) * (1.f / 64.f);
  float d = hn - mu;
  float var = wsum(d * d) * (1.f / 64.f);
  float ho = d * rsqrtf(var + 1e-5f) * gamma[lane] + beta[lane];
  ho += u;
  h[gi] = ho;
  // decoder fastkan + softplus
  float dc0 = cdec[0], dc7 = cdec[cNB - 1];
  float inv_d = (float)(cNB - 1) / (dc7 - dc0);
  float p0 = 0.f, p1 = 0.f, p2 = 0.f;
#pragma unroll
  for (int j = 0; j < cNB; j++) {
    float dd = (ho - cdec[j]) * inv_d;
    float ph = expf(-dd * dd);
    int base = (lane * cNB + j) * 3;
    p0 += ph * W_dec[base + 0];
    p1 += ph * W_dec[base + 1];
    p2 += ph * W_dec[base + 2];
  }
  p0 = wsum(p0);
  p1 = wsum(p1);
  p2 = wsum(p2);
  if (lane == 0) {
    size_t ob = (((size_t)b * cT + t) * cN + n) * 3;
    float v0 = p0 + b_dec[0];
    float v1 = p1 + b_dec[1];
    float v2 = p2 + b_dec[2];
    out[ob + 0] = fmaxf(v0, 0.f) + log1pf(expf(-fabsf(v0)));
    out[ob + 1] = fmaxf(v1, 0.f) + log1pf(expf(-fabsf(v1)));
    out[ob + 2] = fmaxf(v2, 0.f) + log1pf(expf(-fabsf(v2)));
  }
}

extern "C" void kernel_launch(void* const* d_in, const int* in_sizes, int n_in, void* d_out,
                              int out_size, void* d_ws, size_t ws_size, hipStream_t stream) {
  fp x = (fp)d_in[0];
  fp edge_attr = (fp)d_in[1];
  fp c_enc = (fp)d_in[2];
  fp W_enc = (fp)d_in[3];
  fp b_enc = (fp)d_in[4];
  fp W_hop = (fp)d_in[5];
  fp a_src = (fp)d_in[6];
  fp a_dst = (fp)d_in[7];
  fp w_lt1 = (fp)d_in[8];
  fp b_lt1 = (fp)d_in[9];
  fp w_lt2 = (fp)d_in[10];
  fp b_lt2 = (fp)d_in[11];
  fp W_lt = (fp)d_in[12];
  fp W_tau = (fp)d_in[13];
  fp b_tau = (fp)d_in[14];
  fp W_g = (fp)d_in[15];
  fp b_g = (fp)d_in[16];
  fp gamma = (fp)d_in[17];
  fp beta = (fp)d_in[18];
  fp c_dec = (fp)d_in[19];
  fp W_dec = (fp)d_in[20];
  fp b_dec = (fp)d_in[21];
  fp h0 = (fp)d_in[22];
  const int* eidx = (const int*)d_in[23];
  const int* esrc_in = eidx;
  const int* edst_in = eidx + cE;

  float* fws = (float*)d_ws;
  float* h = fws;      fws += cBNH;
  float* cur = fws;    fws += cBNH;
  float* hw = fws;     fws += cBNH;
  float* khout = fws;  fws += cBNH;
  float* agg = fws;    fws += cBNH;
  float* ssrc = fws;   fws += cBN;
  float* sdst = fws;   fws += cBN;
  float* gcsr = fws;   fws += cE;
  int* iws = (int*)fws;
  int* esrc = iws;     iws += cE;
  int* row_ptr = iws;  iws += cN + 1;
  int* cursor = iws;   iws += cN;
  int* counts = iws;   iws += cN;

  k_zero_i32<<<(cN + 255) / 256, 256, 0, stream>>>(counts, cN);
  k_count<<<(cE + 255) / 256, 256, 0, stream>>>(edst_in, counts);
  k_scan<<<1, 1024, 0, stream>>>(counts, row_ptr, cursor);
  k_scatter<<<(cE + 255) / 256, 256, 0, stream>>>(esrc_in, edst_in, edge_attr, w_lt1, b_lt1,
                                                  w_lt2, b_lt2, cursor, esrc, gcsr);
  k_init_h<<<(cBNH + 255) / 256, 256, 0, stream>>>(h, h0);

  dim3 gridN(cBN / 4);  // 5000 blocks, 4 waves each, wave per node — exact cover
  for (int t = 0; t < cT; t++) {
    for (int k = 0; k < cK; k++) {
      k_hop_mat<<<gridN, 256, 0, stream>>>(k == 0 ? h : cur, W_hop + (size_t)k * cH * cH,
                                           a_src + k * cH, a_dst + k * cH, hw, ssrc, sdst);
      k_hop_agg<<<gridN, 256, 0, stream>>>(hw, ssrc, sdst, row_ptr, esrc, cur, khout, k);
    }
    k_larval<<<gridN, 256, 0, stream>>>(h, row_ptr, esrc, gcsr, agg);
    k_cell<<<gridN, 256, 0, stream>>>(x, t, h, khout, agg, row_ptr, W_lt, W_tau, b_tau, W_g, b_g,
                                      gamma, beta, c_enc, W_enc, b_enc, c_dec, W_dec, b_dec,
                                      (float*)d_out);
  }
}